// Round 9
// baseline (435.665 us; speedup 1.0000x reference)
//
#include <hip/hip_runtime.h>
#include <stdint.h>

#define M_DIM 16384
#define N_DIM 4096
#define K_DIM 4096

#define BM 256
#define BN 256
#define BK 128
#define NT (K_DIM / BK)  // 32 K-tiles

typedef int i32x4 __attribute__((ext_vector_type(4)));

// ---- async global->LDS 16B (dest = wave-uniform base, HW adds lane*16) ----
__device__ __forceinline__ void async16(const uint8_t* g, uint8_t* l) {
    __builtin_amdgcn_global_load_lds(
        (const __attribute__((address_space(1))) void*)g,
        (__attribute__((address_space(3))) void*)l,
        16, 0, 0);
}

// ---------------- weight pack: int32 -> int8 ----------------
__global__ __launch_bounds__(256) void pack_w_kernel(const int* __restrict__ w32,
                                                     uint32_t* __restrict__ w8,
                                                     int n4) {
    int i = blockIdx.x * 256 + threadIdx.x;
    if (i < n4) {
        const int4 v = reinterpret_cast<const int4*>(w32)[i];
        uint32_t p = (uint32_t)(v.x & 255) | ((uint32_t)(v.y & 255) << 8) |
                     ((uint32_t)(v.z & 255) << 16) | ((uint32_t)(v.w & 255) << 24);
        w8[i] = p;
    }
}

// ---------------- per-row dynamic activation quant ----------------
__global__ __launch_bounds__(256) void quant_kernel(const float* __restrict__ x,
                                                    uint32_t* __restrict__ xq,
                                                    float* __restrict__ xscale) {
    const int m = blockIdx.x;
    const int t = threadIdx.x;
    const float4* row = reinterpret_cast<const float4*>(x + (size_t)m * K_DIM);
    float4 v[4];
    float amax = 0.0f;
#pragma unroll
    for (int i = 0; i < 4; ++i) {
        v[i] = row[t + i * 256];
        amax = fmaxf(amax, fmaxf(fmaxf(fabsf(v[i].x), fabsf(v[i].y)),
                                 fmaxf(fabsf(v[i].z), fabsf(v[i].w))));
    }
#pragma unroll
    for (int off = 32; off > 0; off >>= 1) amax = fmaxf(amax, __shfl_xor(amax, off));
    __shared__ float smax[4];
    if ((t & 63) == 0) smax[t >> 6] = amax;
    __syncthreads();
    amax = fmaxf(fmaxf(smax[0], smax[1]), fmaxf(smax[2], smax[3]));
    const float scale = amax / 127.0f;
    const float s = fmaxf(scale, 1e-8f);
    if (t == 0) xscale[m] = scale;
    uint32_t* orow = xq + (size_t)m * (K_DIM / 4);
#pragma unroll
    for (int i = 0; i < 4; ++i) {
        int q0 = __float2int_rn(v[i].x / s);
        int q1 = __float2int_rn(v[i].y / s);
        int q2 = __float2int_rn(v[i].z / s);
        int q3 = __float2int_rn(v[i].w / s);
        q0 = max(-127, min(127, q0));
        q1 = max(-127, min(127, q1));
        q2 = max(-127, min(127, q2));
        q3 = max(-127, min(127, q3));
        uint32_t p = (uint32_t)(q0 & 255) | ((uint32_t)(q1 & 255) << 8) |
                     ((uint32_t)(q2 & 255) << 16) | ((uint32_t)(q3 & 255) << 24);
        orow[t + i * 256] = p;
    }
}

// ----- int8 GEMM, 256x256: A via LDS, B direct global->VGPR (flatmm) ------
// 512 thr = 8 waves (2M x 4N), per-wave 128x64, mfma_i32_16x16x64.
// LDS 64KB: A double-buffer only (2x32KB). B frags loaded per-wave from
// global (16 rows x 64B per load-group, L2-hot via col-major XCD chunks),
// issued ~1 tile ahead; each kk-half reg set reloaded right after its last
// MFMA use (no reg double-buffer). LDS pipe/tile drops 2550->~1790 cy,
// below MFMA's 2611 cy.
// Per tile T (cur = A[T&1]; program order and vmcnt audit):
//  1 LGKM0                 ; A-kk0(T) frags ready (read at T-1 tail)
//  2 read A-kk1(T) [8 ds]  ; drains under cluster0
//  3 CLUSTER(0)            ; bf0 = B(T,kk0): compiler auto-vmcnt (age ~1 tile)
//  4 load B(T+1,kk0) [4]   ; -> bf0 (dead after step 3); compiler-managed RAW
//  5 LGKM0                 ; A-kk1 ready
//  6 VMCNT(8)              ; outstanding old->new: A(T+1)[4], B(T,kk1)[4],
//                            B(T+1,kk0)[4] -> drains A(T+1) (age ~1 tile)
//  7 BAR                   ; cur reads done (step 5 all waves); A(T+1) landed
//  8 stage A(T+2)->cur [4 async16]
//  9 read A-kk0(T+1) [8 ds]; from nxt buf; drains under cluster1
// 10 CLUSTER(1)            ; bf1 = B(T,kk1): compiler auto-vmcnt (age ~1 tile)
// 11 load B(T+1,kk1) [4]   ; -> bf1 (dead after step 10)
// Swizzle (A only): LDS(row r, unit p) holds global unit p^(r&7); proven
// 0-conflict. XCD chunks col-major: same-XCD blocks share B col-panel
// (2MB <= 4MB L2); A streams via latency-tolerant LDS path.
__global__ __launch_bounds__(512, 2) void gemm_kernel(
    const uint8_t* __restrict__ Aq, const float* __restrict__ ascale,
    const uint8_t* __restrict__ Bq, const float* __restrict__ wscale,
    float* __restrict__ out) {
    __shared__ uint8_t lds[2 * BM * BK];  // A0|A1
    uint8_t* ldsA0 = lds;
    uint8_t* ldsA1 = lds + BM * BK;

    const int tid = threadIdx.x;
    const int lane = tid & 63;
    const int w = tid >> 6;
    const int wr = w >> 2;     // 0..1 -> M offset wr*128
    const int wc = w & 3;      // 0..3 -> N offset wc*64
    const int lr = lane & 15;  // row within 16x16 fragment
    const int lg = lane >> 4;  // k-group 0..3 (16B each)

    // XCD-aware bijective swizzle, col-major chunks: 1024 blocks, each XCD
    // gets 128 consecutive swz = 2 B col-panels (2MB, L2-resident)
    const int bid = blockIdx.x;
    const int swz = (bid & 7) * (1024 / 8) + (bid >> 3);
    const size_t col0 = (size_t)(swz >> 6) * BN;  // 16 N-tiles (major)
    const size_t row0 = (size_t)(swz & 63) * BM;  // 64 M-tiles (minor)
    const uint8_t* Ab = Aq + row0 * K_DIM;

    // per-lane B base: row (col0 + wc*64 + lr), k-byte lg*16
    const uint8_t* bRow = Bq + (col0 + wc * 64 + lr) * (size_t)K_DIM + lg * 16;

    i32x4 acc[8][4];
#pragma unroll
    for (int i = 0; i < 8; ++i)
#pragma unroll
        for (int j = 0; j < 4; ++j) acc[i][j] = (i32x4){0, 0, 0, 0};

    // stage a full 256x128B A panel (32KB = 2048 x 16B units): 4 iters x 512
#define STAGE_P(DST, KT)                                                         \
    do {                                                                         \
        _Pragma("unroll") for (int it_ = 0; it_ < 4; ++it_) {                    \
            const int idx_ = it_ * 512 + tid;                                    \
            const int m_ = idx_ >> 3, p_ = idx_ & 7;                             \
            async16(Ab + (size_t)m_ * K_DIM + (KT) * BK + ((p_ ^ (m_ & 7)) << 4),\
                    (DST) + (it_ * 512 + w * 64) * 16);                          \
        }                                                                        \
    } while (0)

#define READ_AK(BUF, KK)                                                         \
    do {                                                                         \
        _Pragma("unroll") for (int q_ = 0; q_ < 8; ++q_) {                       \
            const int r_ = wr * 128 + q_ * 16 + lr;                              \
            const int u_ = (KK) * 4 + lg;                                        \
            afk[KK][q_] = *reinterpret_cast<const i32x4*>(                       \
                (BUF) + r_ * BK + ((u_ ^ (r_ & 7)) << 4));                       \
        }                                                                        \
    } while (0)

    // B frags direct from global: bfk[KK][p] = B[wc*64+p*16+lr][kt*128+KK*64+lg*16]
#define LOADB(KK, KT)                                                            \
    do {                                                                         \
        _Pragma("unroll") for (int p_ = 0; p_ < 4; ++p_) {                       \
            bfk[KK][p_] = *reinterpret_cast<const i32x4*>(                       \
                bRow + (size_t)p_ * 16 * K_DIM + (KT) * BK + (KK) * 64);         \
        }                                                                        \
    } while (0)

#define CLUSTER(KK)                                                              \
    do {                                                                         \
        __builtin_amdgcn_s_setprio(1);                                           \
        _Pragma("unroll") for (int q_ = 0; q_ < 8; ++q_)                         \
        _Pragma("unroll") for (int p_ = 0; p_ < 4; ++p_)                         \
            acc[q_][p_] = __builtin_amdgcn_mfma_i32_16x16x64_i8(                 \
                afk[KK][q_], bfk[KK][p_], acc[q_][p_], 0, 0, 0);                 \
        __builtin_amdgcn_s_setprio(0);                                           \
    } while (0)

#define BAR __builtin_amdgcn_s_barrier()
#define VMCNT(N) asm volatile("s_waitcnt vmcnt(" #N ")" ::: "memory")
#define LGKM0                                              \
    do {                                                   \
        asm volatile("s_waitcnt lgkmcnt(0)" ::: "memory"); \
        __builtin_amdgcn_sched_barrier(0);                 \
    } while (0)

    // one tile of the steady-state schedule (see header comment)
#define TILE_ONE(CUR, NXT, TB, TA2)                                              \
    do {                                                                         \
        LGKM0;                                                                   \
        READ_AK(CUR, 1);                                                         \
        CLUSTER(0);                                                              \
        LOADB(0, TB);                                                            \
        LGKM0;                                                                   \
        VMCNT(8);                                                                \
        BAR;                                                                     \
        STAGE_P(CUR, TA2);                                                       \
        READ_AK(NXT, 0);                                                         \
        CLUSTER(1);                                                              \
        LOADB(1, TB);                                                            \
    } while (0)

    i32x4 afk[2][8], bfk[2][4];

    // ---- prologue: A(0)->A0, A(1)->A1, B(0) both halves; full drain ----
    STAGE_P(ldsA0, 0);
    STAGE_P(ldsA1, 1);
    LOADB(0, 0);
    LOADB(1, 0);
    VMCNT(0);
    BAR;
    READ_AK(ldsA0, 0);  // A-kk0(0)

#pragma unroll 1
    for (int it2 = 0; it2 < NT / 2; ++it2) {
        const int T = 2 * it2;
        const int Tb1 = (T + 1 < NT) ? T + 1 : NT - 1;  // clamped tail (dead)
        const int Ta2 = (T + 2 < NT) ? T + 2 : NT - 1;
        const int Tb2 = Ta2;
        const int Ta3 = (T + 3 < NT) ? T + 3 : NT - 1;

        TILE_ONE(ldsA0, ldsA1, Tb1, Ta2);  // tile T
        TILE_ONE(ldsA1, ldsA0, Tb2, Ta3);  // tile T+1
    }

    // ---- epilogue: C/D layout col = lane&15, row = (lane>>4)*4 + reg ----
    const float* asp = ascale + row0 + wr * 128;
    const float* wsp = wscale + col0 + wc * 64;
    float wsv[4];
#pragma unroll
    for (int nf = 0; nf < 4; ++nf) wsv[nf] = wsp[nf * 16 + lr];
    float* outBase = out + (row0 + wr * 128) * (size_t)N_DIM + col0 + wc * 64;
#pragma unroll
    for (int mf = 0; mf < 8; ++mf) {
#pragma unroll
        for (int j = 0; j < 4; ++j) {
            const int r = mf * 16 + lg * 4 + j;
            const float av = asp[r];
            float* orow = outBase + (size_t)r * N_DIM;
#pragma unroll
            for (int nf = 0; nf < 4; ++nf) {
                orow[nf * 16 + lr] = (float)acc[mf][nf][j] * av * wsv[nf];
            }
        }
    }
#undef STAGE_P
#undef READ_AK
#undef LOADB
#undef CLUSTER
#undef TILE_ONE
#undef BAR
#undef VMCNT
#undef LGKM0
}

extern "C" void kernel_launch(void* const* d_in, const int* in_sizes, int n_in,
                              void* d_out, int out_size, void* d_ws, size_t ws_size,
                              hipStream_t stream) {
    const float* x = (const float*)d_in[0];
    const int* w32 = (const int*)d_in[1];
    const float* wscale = (const float*)d_in[2];
    float* out = (float*)d_out;

    uint8_t* ws = (uint8_t*)d_ws;
    uint32_t* xq = (uint32_t*)ws;                                  // 64 MiB
    float* xscale = (float*)(ws + (size_t)M_DIM * K_DIM);          // 64 KiB
    uint8_t* wq = ws + (size_t)M_DIM * K_DIM + (size_t)M_DIM * 4;  // 16 MiB

    pack_w_kernel<<<dim3((N_DIM * K_DIM / 4 + 255) / 256), 256, 0, stream>>>(
        w32, (uint32_t*)wq, N_DIM * K_DIM / 4);
    quant_kernel<<<dim3(M_DIM), 256, 0, stream>>>(x, xq, xscale);
    gemm_kernel<<<dim3((M_DIM / BM) * (N_DIM / BN)), 512, 0, stream>>>(
        (const uint8_t*)xq, xscale, wq, wscale, out);
}

// Round 10
// 346.857 us; speedup vs baseline: 1.2560x; 1.2560x over previous
//
#include <hip/hip_runtime.h>
#include <stdint.h>

#define M_DIM 16384
#define N_DIM 4096
#define K_DIM 4096

#define BM 256
#define BN 256
#define BK 128
#define NT (K_DIM / BK)  // 32 K-tiles

typedef int i32x4 __attribute__((ext_vector_type(4)));

// ---- async global->LDS 16B (dest = wave-uniform base, HW adds lane*16) ----
__device__ __forceinline__ void async16(const uint8_t* g, uint8_t* l) {
    __builtin_amdgcn_global_load_lds(
        (const __attribute__((address_space(1))) void*)g,
        (__attribute__((address_space(3))) void*)l,
        16, 0, 0);
}

// ---------------- weight pack: int32 -> int8 ----------------
__global__ __launch_bounds__(256) void pack_w_kernel(const int* __restrict__ w32,
                                                     uint32_t* __restrict__ w8,
                                                     int n4) {
    int i = blockIdx.x * 256 + threadIdx.x;
    if (i < n4) {
        const int4 v = reinterpret_cast<const int4*>(w32)[i];
        uint32_t p = (uint32_t)(v.x & 255) | ((uint32_t)(v.y & 255) << 8) |
                     ((uint32_t)(v.z & 255) << 16) | ((uint32_t)(v.w & 255) << 24);
        w8[i] = p;
    }
}

// ---------------- per-row dynamic activation quant ----------------
__global__ __launch_bounds__(256) void quant_kernel(const float* __restrict__ x,
                                                    uint32_t* __restrict__ xq,
                                                    float* __restrict__ xscale) {
    const int m = blockIdx.x;
    const int t = threadIdx.x;
    const float4* row = reinterpret_cast<const float4*>(x + (size_t)m * K_DIM);
    float4 v[4];
    float amax = 0.0f;
#pragma unroll
    for (int i = 0; i < 4; ++i) {
        v[i] = row[t + i * 256];
        amax = fmaxf(amax, fmaxf(fmaxf(fabsf(v[i].x), fabsf(v[i].y)),
                                 fmaxf(fabsf(v[i].z), fabsf(v[i].w))));
    }
#pragma unroll
    for (int off = 32; off > 0; off >>= 1) amax = fmaxf(amax, __shfl_xor(amax, off));
    __shared__ float smax[4];
    if ((t & 63) == 0) smax[t >> 6] = amax;
    __syncthreads();
    amax = fmaxf(fmaxf(smax[0], smax[1]), fmaxf(smax[2], smax[3]));
    const float scale = amax / 127.0f;
    const float s = fmaxf(scale, 1e-8f);
    if (t == 0) xscale[m] = scale;
    uint32_t* orow = xq + (size_t)m * (K_DIM / 4);
#pragma unroll
    for (int i = 0; i < 4; ++i) {
        int q0 = __float2int_rn(v[i].x / s);
        int q1 = __float2int_rn(v[i].y / s);
        int q2 = __float2int_rn(v[i].z / s);
        int q3 = __float2int_rn(v[i].w / s);
        q0 = max(-127, min(127, q0));
        q1 = max(-127, min(127, q1));
        q2 = max(-127, min(127, q2));
        q3 = max(-127, min(127, q3));
        uint32_t p = (uint32_t)(q0 & 255) | ((uint32_t)(q1 & 255) << 8) |
                     ((uint32_t)(q2 & 255) << 16) | ((uint32_t)(q3 & 255) << 24);
        orow[t + i * 256] = p;
    }
}

// ------- int8 GEMM, r8 structure + sched_group_barrier interleave ---------
// 512 thr = 8 waves (2M x 4N), per-wave 128x64, mfma_i32_16x16x64.
// LDS 128KB: A0|A1|B0|B1 (32KB each, dbuf). 1 BAR + 2 lgkm + 1 vmcnt / tile.
// NEW vs r8 (the only change): each cluster region's emitted instruction
// stream is pinned by sched_group_barrier to
//   [4 VMEM stage loads] then 12 x [2 MFMA, 1 ds_read] then [8 MFMA]
// so the LDS pipe (~2800 cy/tile) and MFMA pipe (~2483 cy/tile) run
// CONCURRENTLY instead of the serial sum (~5008 cy measured r3/r8).
// Legality: cluster(F) depends only on frag set F (loaded & lgkm'd last
// region); the 12 ds_reads fill set F^1 (dead since its last cluster).
// Swizzle: LDS(row r, unit p) holds global unit p^(r&7) (pre-swizzled global
// source, linear LDS dest, XOR on ds_read). Proven 0 bank conflicts.
__global__ __launch_bounds__(512, 2) void gemm_kernel(
    const uint8_t* __restrict__ Aq, const float* __restrict__ ascale,
    const uint8_t* __restrict__ Bq, const float* __restrict__ wscale,
    float* __restrict__ out) {
    __shared__ uint8_t lds[4 * BM * BK];  // A0|A1|B0|B1
    uint8_t* ldsA0 = lds;
    uint8_t* ldsA1 = lds + BM * BK;
    uint8_t* ldsB0 = lds + 2 * BM * BK;
    uint8_t* ldsB1 = lds + 3 * BM * BK;

    const int tid = threadIdx.x;
    const int lane = tid & 63;
    const int w = tid >> 6;
    const int wr = w >> 2;     // 0..1 -> M offset wr*128
    const int wc = w & 3;      // 0..3 -> N offset wc*64
    const int lr = lane & 15;  // row within 16x16 fragment
    const int lg = lane >> 4;  // k-group 0..3 (16B each)

    // XCD-aware bijective swizzle (1024 blocks, 1024%8==0)
    const int bid = blockIdx.x;
    const int swz = (bid & 7) * (1024 / 8) + (bid >> 3);
    const size_t row0 = (size_t)(swz >> 4) * BM;  // 64 M-tiles
    const size_t col0 = (size_t)(swz & 15) * BN;  // 16 N-tiles
    const uint8_t* Ab = Aq + row0 * K_DIM;
    const uint8_t* Bb = Bq + col0 * K_DIM;

    i32x4 acc[8][4];
#pragma unroll
    for (int i = 0; i < 8; ++i)
#pragma unroll
        for (int j = 0; j < 4; ++j) acc[i][j] = (i32x4){0, 0, 0, 0};

    // stage a full 256x128B panel (32KB = 2048 x 16B units): 4 iters x 512 thr
#define STAGE_P(BASE, DST, KT)                                                   \
    do {                                                                         \
        _Pragma("unroll") for (int it_ = 0; it_ < 4; ++it_) {                    \
            const int idx_ = it_ * 512 + tid;                                    \
            const int m_ = idx_ >> 3, p_ = idx_ & 7;                             \
            async16((BASE) + (size_t)m_ * K_DIM + (KT) * BK +                    \
                        ((p_ ^ (m_ & 7)) << 4),                                  \
                    (DST) + (it_ * 512 + w * 64) * 16);                          \
        }                                                                        \
    } while (0)

    // kk-half frag reads: A 8 + B 4 b128 into afk[F]/bfk[F]
#define READ_K(BUFA, BUFB, KK, F)                                                \
    do {                                                                         \
        _Pragma("unroll") for (int q_ = 0; q_ < 8; ++q_) {                       \
            const int r_ = wr * 128 + q_ * 16 + lr;                              \
            const int u_ = (KK) * 4 + lg;                                        \
            afk[F][q_] = *reinterpret_cast<const i32x4*>(                        \
                (BUFA) + r_ * BK + ((u_ ^ (r_ & 7)) << 4));                      \
        }                                                                        \
        _Pragma("unroll") for (int p_ = 0; p_ < 4; ++p_) {                       \
            const int r_ = wc * 64 + p_ * 16 + lr;                               \
            const int u_ = (KK) * 4 + lg;                                        \
            bfk[F][p_] = *reinterpret_cast<const i32x4*>(                        \
                (BUFB) + r_ * BK + ((u_ ^ (r_ & 7)) << 4));                      \
        }                                                                        \
    } while (0)

#define CLUSTER(F)                                                               \
    do {                                                                         \
        __builtin_amdgcn_s_setprio(1);                                           \
        _Pragma("unroll") for (int q_ = 0; q_ < 8; ++q_)                         \
        _Pragma("unroll") for (int p_ = 0; p_ < 4; ++p_)                         \
            acc[q_][p_] = __builtin_amdgcn_mfma_i32_16x16x64_i8(                 \
                afk[F][q_], bfk[F][p_], acc[q_][p_], 0, 0, 0);                   \
        __builtin_amdgcn_s_setprio(0);                                           \
    } while (0)

    // scheduler slot spec for one region: 4 VMEM (stage loads) up front,
    // then 12 x {2 MFMA, 1 DS_READ}, then the remaining 8 MFMA.
    // Masks: MFMA=0x8, VMEM_READ=0x20, DS_READ=0x100 (LLVM SchedGroupMask).
#define SGB __builtin_amdgcn_sched_group_barrier
#define INTERLEAVE_SPEC                                                          \
    do {                                                                         \
        SGB(0x20, 4, 0);                                                         \
        _Pragma("unroll") for (int i_ = 0; i_ < 12; ++i_) {                      \
            SGB(0x8, 2, 0);                                                      \
            SGB(0x100, 1, 0);                                                    \
        }                                                                        \
        SGB(0x8, 8, 0);                                                          \
    } while (0)

#define BAR __builtin_amdgcn_s_barrier()
#define VMCNT(N) asm volatile("s_waitcnt vmcnt(" #N ")" ::: "memory")
#define LGKM0                                              \
    do {                                                   \
        asm volatile("s_waitcnt lgkmcnt(0)" ::: "memory"); \
        __builtin_amdgcn_sched_barrier(0);                 \
    } while (0)

    i32x4 afk[2][8], bfk[2][4];

    // ---- prologue: tile0 full + A(1); leave A(1) in flight ----
    STAGE_P(Ab, ldsA0, 0);
    STAGE_P(Bb, ldsB0, 0);
    STAGE_P(Ab, ldsA1, 1);
    VMCNT(4);  // tile0 landed; A(1)'s 4 in flight
    BAR;
    READ_K(ldsA0, ldsB0, 0, 0);  // kk0(0) -> f0

#pragma unroll 1
    for (int it2 = 0; it2 < NT / 2; ++it2) {
        const int T = 2 * it2;
        const int Tp2 = (T + 2 < NT) ? T + 2 : NT - 1;  // clamped tail stages
        const int Tp3 = (T + 3 < NT) ? T + 3 : NT - 1;  // (dead-region writes)

        // ======== tile T (cur = A0/B0) ========
        LGKM0;                        // f0(T) ready; region open
        STAGE_P(Bb, ldsB1, T + 1);    // 4 VMEM
        READ_K(ldsA0, ldsB0, 1, 1);   // 12 DS -> f1
        CLUSTER(0);                   // 32 MFMA on f0
        INTERLEAVE_SPEC;
        LGKM0;                        // f1(T) ready; region close
        VMCNT(0);                     // aged: A(T+1) ~1 tile, B(T+1) ~1 cluster
        BAR;                          // nxt staged; all cur reads done
        STAGE_P(Ab, ldsA0, Tp2);      // 4 VMEM
        READ_K(ldsA1, ldsB1, 0, 0);   // 12 DS -> f0 (tile T+1)
        CLUSTER(1);                   // 32 MFMA on f1
        INTERLEAVE_SPEC;

        // ======== tile T+1 (cur = A1/B1) ========
        LGKM0;
        STAGE_P(Bb, ldsB0, Tp2);
        READ_K(ldsA1, ldsB1, 1, 1);
        CLUSTER(0);
        INTERLEAVE_SPEC;
        LGKM0;
        VMCNT(0);
        BAR;
        STAGE_P(Ab, ldsA1, Tp3);
        READ_K(ldsA0, ldsB0, 0, 0);   // (dead at final iter)
        CLUSTER(1);
        INTERLEAVE_SPEC;
    }

    // ---- epilogue: C/D layout col = lane&15, row = (lane>>4)*4 + reg ----
    const float* asp = ascale + row0 + wr * 128;
    const float* wsp = wscale + col0 + wc * 64;
    float wsv[4];
#pragma unroll
    for (int nf = 0; nf < 4; ++nf) wsv[nf] = wsp[nf * 16 + lr];
    float* outBase = out + (row0 + wr * 128) * (size_t)N_DIM + col0 + wc * 64;
#pragma unroll
    for (int mf = 0; mf < 8; ++mf) {
#pragma unroll
        for (int j = 0; j < 4; ++j) {
            const int r = mf * 16 + lg * 4 + j;
            const float av = asp[r];
            float* orow = outBase + (size_t)r * N_DIM;
#pragma unroll
            for (int nf = 0; nf < 4; ++nf) {
                orow[nf * 16 + lr] = (float)acc[mf][nf][j] * av * wsv[nf];
            }
        }
    }
#undef STAGE_P
#undef READ_K
#undef CLUSTER
#undef INTERLEAVE_SPEC
#undef SGB
#undef BAR
#undef VMCNT
#undef LGKM0
}

extern "C" void kernel_launch(void* const* d_in, const int* in_sizes, int n_in,
                              void* d_out, int out_size, void* d_ws, size_t ws_size,
                              hipStream_t stream) {
    const float* x = (const float*)d_in[0];
    const int* w32 = (const int*)d_in[1];
    const float* wscale = (const float*)d_in[2];
    float* out = (float*)d_out;

    uint8_t* ws = (uint8_t*)d_ws;
    uint32_t* xq = (uint32_t*)ws;                                  // 64 MiB
    float* xscale = (float*)(ws + (size_t)M_DIM * K_DIM);          // 64 KiB
    uint8_t* wq = ws + (size_t)M_DIM * K_DIM + (size_t)M_DIM * 4;  // 16 MiB

    pack_w_kernel<<<dim3((N_DIM * K_DIM / 4 + 255) / 256), 256, 0, stream>>>(
        w32, (uint32_t*)wq, N_DIM * K_DIM / 4);
    quant_kernel<<<dim3(M_DIM), 256, 0, stream>>>(x, xq, xscale);
    gemm_kernel<<<dim3((M_DIM / BM) * (N_DIM / BN)), 512, 0, stream>>>(
        (const uint8_t*)xq, xscale, wq, wscale, out);
}

// Round 11
// 343.776 us; speedup vs baseline: 1.2673x; 1.0090x over previous
//
#include <hip/hip_runtime.h>
#include <stdint.h>

#define M_DIM 16384
#define N_DIM 4096
#define K_DIM 4096

#define BM 256
#define BN 256
#define BK 128
#define NT (K_DIM / BK)  // 32 K-tiles

typedef int i32x4 __attribute__((ext_vector_type(4)));

// ---- async global->LDS 16B (dest = wave-uniform base, HW adds lane*16) ----
__device__ __forceinline__ void async16(const uint8_t* g, uint8_t* l) {
    __builtin_amdgcn_global_load_lds(
        (const __attribute__((address_space(1))) void*)g,
        (__attribute__((address_space(3))) void*)l,
        16, 0, 0);
}

// ---------------- weight pack: int32 -> int8 ----------------
__global__ __launch_bounds__(256) void pack_w_kernel(const int* __restrict__ w32,
                                                     uint32_t* __restrict__ w8,
                                                     int n4) {
    int i = blockIdx.x * 256 + threadIdx.x;
    if (i < n4) {
        const int4 v = reinterpret_cast<const int4*>(w32)[i];
        uint32_t p = (uint32_t)(v.x & 255) | ((uint32_t)(v.y & 255) << 8) |
                     ((uint32_t)(v.z & 255) << 16) | ((uint32_t)(v.w & 255) << 24);
        w8[i] = p;
    }
}

// ---------------- per-row dynamic activation quant ----------------
__global__ __launch_bounds__(256) void quant_kernel(const float* __restrict__ x,
                                                    uint32_t* __restrict__ xq,
                                                    float* __restrict__ xscale) {
    const int m = blockIdx.x;
    const int t = threadIdx.x;
    const float4* row = reinterpret_cast<const float4*>(x + (size_t)m * K_DIM);
    float4 v[4];
    float amax = 0.0f;
#pragma unroll
    for (int i = 0; i < 4; ++i) {
        v[i] = row[t + i * 256];
        amax = fmaxf(amax, fmaxf(fmaxf(fabsf(v[i].x), fabsf(v[i].y)),
                                 fmaxf(fabsf(v[i].z), fabsf(v[i].w))));
    }
#pragma unroll
    for (int off = 32; off > 0; off >>= 1) amax = fmaxf(amax, __shfl_xor(amax, off));
    __shared__ float smax[4];
    if ((t & 63) == 0) smax[t >> 6] = amax;
    __syncthreads();
    amax = fmaxf(fmaxf(smax[0], smax[1]), fmaxf(smax[2], smax[3]));
    const float scale = amax / 127.0f;
    const float s = fmaxf(scale, 1e-8f);
    if (t == 0) xscale[m] = scale;
    uint32_t* orow = xq + (size_t)m * (K_DIM / 4);
#pragma unroll
    for (int i = 0; i < 4; ++i) {
        int q0 = __float2int_rn(v[i].x / s);
        int q1 = __float2int_rn(v[i].y / s);
        int q2 = __float2int_rn(v[i].z / s);
        int q3 = __float2int_rn(v[i].w / s);
        q0 = max(-127, min(127, q0));
        q1 = max(-127, min(127, q1));
        q2 = max(-127, min(127, q2));
        q3 = max(-127, min(127, q3));
        uint32_t p = (uint32_t)(q0 & 255) | ((uint32_t)(q1 & 255) << 8) |
                     ((uint32_t)(q2 & 255) << 16) | ((uint32_t)(q3 & 255) << 24);
        orow[t + i * 256] = p;
    }
}

// ------- int8 GEMM, r8 pipeline + ANTI-PHASE wave groups ------------------
// 512 thr = 8 waves (2M x 4N), per-wave 128x64, mfma_i32_16x16x64.
// LDS 128KB: A0|A1|B0|B1 (32KB each, dbuf). 1 BAR + 2 lgkm + 1 vmcnt / tile.
// NEW vs r8 (the only change): waves with (w>>2)==0 consume kk halves in
// order (kk0,kk1); waves with (w>>2)==1 in order (kk1,kk0). Wave i maps to
// SIMD i&3, so each SIMD hosts one wave of each group -> while one wave is
// in its ds_read/lgkm phase the other runs its 32-MFMA cluster: LDS pipe
// (~2050 cy/tile/CU) and MFMA pipe (~2611 cy/tile/CU) overlap instead of
// summing (measured 5062 cy serial in r3/r8/r10).
// Legality: the full tile (both kk halves) is staged + vmcnt'd + BAR'd
// before any read of it; reads of the same LDS buffer commute; every
// LGKM0/VMCNT/BAR sits at the same program point in both variants, so the
// r8 hazard audit carries over verbatim.
// Swizzle: LDS(row r, unit p) holds global unit p^(r&7) (pre-swizzled global
// source, linear LDS dest, XOR on ds_read). Proven 0 bank conflicts.
__global__ __launch_bounds__(512, 2) void gemm_kernel(
    const uint8_t* __restrict__ Aq, const float* __restrict__ ascale,
    const uint8_t* __restrict__ Bq, const float* __restrict__ wscale,
    float* __restrict__ out) {
    __shared__ uint8_t lds[4 * BM * BK];  // A0|A1|B0|B1
    uint8_t* ldsA0 = lds;
    uint8_t* ldsA1 = lds + BM * BK;
    uint8_t* ldsB0 = lds + 2 * BM * BK;
    uint8_t* ldsB1 = lds + 3 * BM * BK;

    const int tid = threadIdx.x;
    const int lane = tid & 63;
    const int w = tid >> 6;
    const int wr = w >> 2;     // 0..1 -> M offset wr*128 (also phase group)
    const int wc = w & 3;      // 0..3 -> N offset wc*64
    const int lr = lane & 15;  // row within 16x16 fragment
    const int lg = lane >> 4;  // k-group 0..3 (16B each)

    // XCD-aware bijective swizzle (1024 blocks, 1024%8==0)
    const int bid = blockIdx.x;
    const int swz = (bid & 7) * (1024 / 8) + (bid >> 3);
    const size_t row0 = (size_t)(swz >> 4) * BM;  // 64 M-tiles
    const size_t col0 = (size_t)(swz & 15) * BN;  // 16 N-tiles
    const uint8_t* Ab = Aq + row0 * K_DIM;
    const uint8_t* Bb = Bq + col0 * K_DIM;

    i32x4 acc[8][4];
#pragma unroll
    for (int i = 0; i < 8; ++i)
#pragma unroll
        for (int j = 0; j < 4; ++j) acc[i][j] = (i32x4){0, 0, 0, 0};

    // stage a full 256x128B panel (32KB = 2048 x 16B units): 4 iters x 512 thr
#define STAGE_P(BASE, DST, KT)                                                   \
    do {                                                                         \
        _Pragma("unroll") for (int it_ = 0; it_ < 4; ++it_) {                    \
            const int idx_ = it_ * 512 + tid;                                    \
            const int m_ = idx_ >> 3, p_ = idx_ & 7;                             \
            async16((BASE) + (size_t)m_ * K_DIM + (KT) * BK +                    \
                        ((p_ ^ (m_ & 7)) << 4),                                  \
                    (DST) + (it_ * 512 + w * 64) * 16);                          \
        }                                                                        \
    } while (0)

    // kk-half frag reads: A 8 + B 4 b128 into frag set F
#define READ_K(BUFA, BUFB, KK, F)                                                \
    do {                                                                         \
        _Pragma("unroll") for (int q_ = 0; q_ < 8; ++q_) {                       \
            const int r_ = wr * 128 + q_ * 16 + lr;                              \
            const int u_ = (KK) * 4 + lg;                                        \
            afk[F][q_] = *reinterpret_cast<const i32x4*>(                        \
                (BUFA) + r_ * BK + ((u_ ^ (r_ & 7)) << 4));                      \
        }                                                                        \
        _Pragma("unroll") for (int p_ = 0; p_ < 4; ++p_) {                       \
            const int r_ = wc * 64 + p_ * 16 + lr;                               \
            const int u_ = (KK) * 4 + lg;                                        \
            bfk[F][p_] = *reinterpret_cast<const i32x4*>(                        \
                (BUFB) + r_ * BK + ((u_ ^ (r_ & 7)) << 4));                      \
        }                                                                        \
    } while (0)

#define CLUSTER(F)                                                               \
    do {                                                                         \
        __builtin_amdgcn_s_setprio(1);                                           \
        _Pragma("unroll") for (int q_ = 0; q_ < 8; ++q_)                         \
        _Pragma("unroll") for (int p_ = 0; p_ < 4; ++p_)                         \
            acc[q_][p_] = __builtin_amdgcn_mfma_i32_16x16x64_i8(                 \
                afk[F][q_], bfk[F][p_], acc[q_][p_], 0, 0, 0);                   \
        __builtin_amdgcn_s_setprio(0);                                           \
    } while (0)

#define BAR __builtin_amdgcn_s_barrier()
#define VMCNT(N) asm volatile("s_waitcnt vmcnt(" #N ")" ::: "memory")
#define LGKM0                                              \
    do {                                                   \
        asm volatile("s_waitcnt lgkmcnt(0)" ::: "memory"); \
        __builtin_amdgcn_sched_barrier(0);                 \
    } while (0)

    // one K-tile; KA = kk consumed first (in F0), KB = kk consumed second (F1)
#define TILE_ONE(CA, CB, NA, NB, TB, TA2, KA, KB)                                \
    do {                                                                         \
        LGKM0;                        /* F0 frags ready */                       \
        STAGE_P(Bb, NB, TB);          /* B(T+1), aged ~1 cluster at vmcnt */     \
        READ_K(CA, CB, KB, 1);        /* second half: drains under cluster0 */   \
        CLUSTER(0);                                                              \
        LGKM0;                        /* F1 ready */                             \
        VMCNT(0);                     /* A(T+1) ~1 tile old, B(T+1) ~1 cluster */\
        BAR;                          /* nxt fully staged; all cur reads done */ \
        STAGE_P(Ab, CA, TA2);         /* A(T+2) -> cur A, ~1 tile window */      \
        READ_K(NA, NB, KA, 0);        /* first half of T+1: under cluster1 */    \
        CLUSTER(1);                                                              \
    } while (0)

#define MAIN_LOOP(KA, KB)                                                        \
    do {                                                                         \
        READ_K(ldsA0, ldsB0, KA, 0);                                             \
        _Pragma("unroll 1") for (int it2 = 0; it2 < NT / 2; ++it2) {             \
            const int T = 2 * it2;                                               \
            const int Tp2 = (T + 2 < NT) ? T + 2 : NT - 1;                       \
            const int Tp3 = (T + 3 < NT) ? T + 3 : NT - 1;                       \
            TILE_ONE(ldsA0, ldsB0, ldsA1, ldsB1, T + 1, Tp2, KA, KB);            \
            TILE_ONE(ldsA1, ldsB1, ldsA0, ldsB0, Tp2, Tp3, KA, KB);              \
        }                                                                        \
    } while (0)

    i32x4 afk[2][8], bfk[2][4];

    // ---- prologue: tile0 full + A(1); leave A(1) in flight ----
    STAGE_P(Ab, ldsA0, 0);
    STAGE_P(Bb, ldsB0, 0);
    STAGE_P(Ab, ldsA1, 1);
    VMCNT(4);  // tile0 landed; A(1)'s 4 in flight
    BAR;

    // anti-phase: group 0 (waves 0-3) consumes kk0 then kk1; group 1 (4-7)
    // kk1 then kk0. Wave i -> SIMD i&3, so each SIMD gets one of each group.
    if (wr == 0) {
        MAIN_LOOP(0, 1);
    } else {
        MAIN_LOOP(1, 0);
    }

    // ---- epilogue: C/D layout col = lane&15, row = (lane>>4)*4 + reg ----
    const float* asp = ascale + row0 + wr * 128;
    const float* wsp = wscale + col0 + wc * 64;
    float wsv[4];
#pragma unroll
    for (int nf = 0; nf < 4; ++nf) wsv[nf] = wsp[nf * 16 + lr];
    float* outBase = out + (row0 + wr * 128) * (size_t)N_DIM + col0 + wc * 64;
#pragma unroll
    for (int mf = 0; mf < 8; ++mf) {
#pragma unroll
        for (int j = 0; j < 4; ++j) {
            const int r = mf * 16 + lg * 4 + j;
            const float av = asp[r];
            float* orow = outBase + (size_t)r * N_DIM;
#pragma unroll
            for (int nf = 0; nf < 4; ++nf) {
                orow[nf * 16 + lr] = (float)acc[mf][nf][j] * av * wsv[nf];
            }
        }
    }
#undef STAGE_P
#undef READ_K
#undef CLUSTER
#undef TILE_ONE
#undef MAIN_LOOP
#undef BAR
#undef VMCNT
#undef LGKM0
}

extern "C" void kernel_launch(void* const* d_in, const int* in_sizes, int n_in,
                              void* d_out, int out_size, void* d_ws, size_t ws_size,
                              hipStream_t stream) {
    const float* x = (const float*)d_in[0];
    const int* w32 = (const int*)d_in[1];
    const float* wscale = (const float*)d_in[2];
    float* out = (float*)d_out;

    uint8_t* ws = (uint8_t*)d_ws;
    uint32_t* xq = (uint32_t*)ws;                                  // 64 MiB
    float* xscale = (float*)(ws + (size_t)M_DIM * K_DIM);          // 64 KiB
    uint8_t* wq = ws + (size_t)M_DIM * K_DIM + (size_t)M_DIM * 4;  // 16 MiB

    pack_w_kernel<<<dim3((N_DIM * K_DIM / 4 + 255) / 256), 256, 0, stream>>>(
        w32, (uint32_t*)wq, N_DIM * K_DIM / 4);
    quant_kernel<<<dim3(M_DIM), 256, 0, stream>>>(x, xq, xscale);
    gemm_kernel<<<dim3((M_DIM / BM) * (N_DIM / BN)), 512, 0, stream>>>(
        (const uint8_t*)xq, xscale, wq, wscale, out);
}